// Round 9
// baseline (2346.906 us; speedup 1.0000x reference)
//
#include <hip/hip_runtime.h>

#define NN 500000
#define NE 8000000
#define NG 5000
#define CH 8
#define NCONV 8
#define HID 128
#define BEPS 1e-5f

#define NBLK 1954                            // (NN+255)/256  (node-major blocks)
#define NBLK2 15625                          // NN*CH/256     (thread-per-(node,c) blocks, exact)
#define SCAN_ELEMS 1024
#define NB_SCAN ((NN + SCAN_ELEMS - 1) / SCAN_ELEMS)   // 489

// ---- bucketed CSR build ----
#define NWIN2 64                             // windows; window w -> XCD (w&7)
#define WNODE 7813                           // nodes/window; 7813*64 = 500032 >= NN
#define PCHUNK 8192                          // edges per partition block
#define NPBLK ((NE + PCHUNK - 1) / PCHUNK)   // 977
#define WCAP 147456                          // per-window bucket capacity (mean ~125K, +17%)
#define NWBLK (NWIN2 * (WCAP / PCHUNK))      // 64*18 = 1152

static inline size_t alignup(size_t v, size_t a) { return (v + a - 1) / a * a; }

// ---------------- init: zero hist + wcur + pooled(f64) ----------------
__global__ void k_init(int* __restrict__ hist, int* __restrict__ wcur,
                       double* __restrict__ pooled) {
    int i = blockIdx.x * 256 + threadIdx.x;
    if (i < NN) hist[i] = 0;
    if (i < NWIN2) wcur[i] = 0;
    if (i < NG * CH) pooled[i] = 0.0;
}

// ---------------- partition: edges -> 64 window buckets, packed (dloc<<19)|src ----------------
__global__ void k_part(const int* __restrict__ src, const int* __restrict__ dst,
                       int* __restrict__ wcur, unsigned int* __restrict__ bucket) {
    __shared__ int cnt[NWIN2], base[NWIN2], lcur[NWIN2];
    int tid = threadIdx.x;
    if (tid < NWIN2) cnt[tid] = 0;
    __syncthreads();
    int start = blockIdx.x * PCHUNK;
    // pass 1: local count per window (dst chunk stays L1/L2-hot for pass 2)
    for (int k = 0; k < PCHUNK / 256; k++) {
        int e = start + k * 256 + tid;
        if (e < NE) atomicAdd(&cnt[dst[e] / WNODE], 1);
    }
    __syncthreads();
    if (tid < NWIN2) {
        base[tid] = atomicAdd(&wcur[tid], cnt[tid]);   // one reservation per window per block
        lcur[tid] = 0;
    }
    __syncthreads();
    // pass 2: emit packed edges into reserved runs
    for (int k = 0; k < PCHUNK / 256; k++) {
        int e = start + k * 256 + tid;
        if (e < NE) {
            int d = dst[e];
            int s = src[e];
            int w = d / WNODE;
            int p = base[w] + atomicAdd(&lcur[w], 1);
            if (p < WCAP)
                bucket[(size_t)w * WCAP + p] = ((unsigned)(d - w * WNODE) << 19) | (unsigned)s;
        }
    }
}

// ---------------- bucketed hist: window w served only by XCD w&7; hist window 31KB L2-local --------
__global__ void k_histb(const int* __restrict__ wcur, const unsigned int* __restrict__ bucket,
                        int* __restrict__ hist) {
    int w = blockIdx.x & (NWIN2 - 1), ck = blockIdx.x >> 6;
    int n = wcur[w]; if (n > WCAP) n = WCAP;
    const unsigned int* bp = bucket + (size_t)w * WCAP;
    int wbase = w * WNODE;
    int b0 = ck * PCHUNK;
    for (int k = 0; k < PCHUNK / 256; k++) {
        int e = b0 + k * 256 + threadIdx.x;
        if (e < n) {
            unsigned p = __builtin_nontemporal_load(bp + e);
            atomicAdd(&hist[wbase + (int)(p >> 19)], 1);
        }
    }
}

// ---------------- scan phase 1 ----------------
__global__ void k_scan1(const int* __restrict__ hist, int* __restrict__ bsum) {
    int b = blockIdx.x, tid = threadIdx.x;
    int base = b * SCAN_ELEMS + tid * 4;
    int s = 0;
#pragma unroll
    for (int k = 0; k < 4; k++) { int i = base + k; if (i < NN) s += hist[i]; }
#pragma unroll
    for (int off = 32; off; off >>= 1) s += __shfl_xor(s, off);
    __shared__ int wsum[4];
    if ((tid & 63) == 0) wsum[tid >> 6] = s;
    __syncthreads();
    if (tid == 0) bsum[b] = wsum[0] + wsum[1] + wsum[2] + wsum[3];
}

// ---------------- scan phase 2 (1 block) ----------------
__global__ void k_scan2(int* __restrict__ bsum) {
    __shared__ int s[512];
    int tid = threadIdx.x;
    int v = (tid < NB_SCAN) ? bsum[tid] : 0;
    s[tid] = v;
    __syncthreads();
    for (int off = 1; off < 512; off <<= 1) {
        int t = (tid >= off) ? s[tid - off] : 0;
        __syncthreads();
        s[tid] += t;
        __syncthreads();
    }
    if (tid < NB_SCAN) bsum[tid] = s[tid] - v;  // exclusive
}

// ---------------- scan phase 3: rowptr/cursor/dinv/dsq ----------------
__global__ void k_scan3(const int* __restrict__ hist, const int* __restrict__ bsum,
                        int* __restrict__ rowptr, int* __restrict__ cursor,
                        float* __restrict__ dinv, float* __restrict__ dsq) {
    int b = blockIdx.x, tid = threadIdx.x;
    int base = b * SCAN_ELEMS + tid * 4;
    int v[4]; int t4 = 0;
#pragma unroll
    for (int k = 0; k < 4; k++) { int i = base + k; v[k] = (i < NN) ? hist[i] : 0; t4 += v[k]; }
    int incl = t4;
#pragma unroll
    for (int off = 1; off < 64; off <<= 1) {
        int t = __shfl_up(incl, off);
        if ((tid & 63) >= off) incl += t;
    }
    __shared__ int wtot[4];
    if ((tid & 63) == 63) wtot[tid >> 6] = incl;
    __syncthreads();
    int woff = 0;
#pragma unroll
    for (int w = 0; w < 4; w++) if (w < (tid >> 6)) woff += wtot[w];
    int excl = incl - t4 + woff + bsum[b];
#pragma unroll
    for (int k = 0; k < 4; k++) {
        int i = base + k;
        if (i < NN) {
            rowptr[i] = excl;
            cursor[i] = excl;
            float deg = (float)(v[k] + 1);     // +1 self-loop
            dinv[i] = rsqrtf(deg);
            dsq[i] = sqrtf(deg);
            excl += v[k];
            if (i == NN - 1) rowptr[NN] = excl;
        }
    }
}

// ---------------- bucketed fill: cursor (31KB) + csr window (~0.5MB) XCD-local ----------------
__global__ void k_fillb(const int* __restrict__ wcur, const unsigned int* __restrict__ bucket,
                        int* __restrict__ cursor, int* __restrict__ csr) {
    int w = blockIdx.x & (NWIN2 - 1), ck = blockIdx.x >> 6;
    int n = wcur[w]; if (n > WCAP) n = WCAP;
    const unsigned int* bp = bucket + (size_t)w * WCAP;
    int wbase = w * WNODE;
    int b0 = ck * PCHUNK;
    for (int k = 0; k < PCHUNK / 256; k++) {
        int e = b0 + k * 256 + threadIdx.x;
        if (e < n) {
            unsigned p = __builtin_nontemporal_load(bp + e);
            int d = wbase + (int)(p >> 19);
            int pos = atomicAdd(&cursor[d], 1);
            csr[pos] = (int)(p & 0x7FFFFu);
        }
    }
}

// ---------------- one-time: S1[n] = sum_{s in N(n)} dinv[s]  (f64 -> stable) ----------------
__global__ void k_s1(const int* __restrict__ rowptr, const int* __restrict__ csr,
                     const float* __restrict__ dinv, float* __restrict__ S1) {
    int n = blockIdx.x * 256 + threadIdx.x;
    if (n >= NN) return;
    int beg = rowptr[n], end = rowptr[n + 1];
    double a = 0.0;
    for (int e = beg; e < end; e++) a += (double)dinv[__builtin_nontemporal_load(csr + e)];
    S1[n] = (float)a;
}

// ---------------- reduce partials -> stats[16] (f64); block b owns slot b ----------------
__global__ void k_rstats(const float* __restrict__ partial, int nblk, double* __restrict__ stats) {
    int slot = blockIdx.x;     // 0..15
    int tid = threadIdx.x;     // 256
    double acc = 0.0;
    for (int j = tid; j < nblk; j += 256) acc += (double)partial[(size_t)j * 16 + slot];
#pragma unroll
    for (int off = 32; off; off >>= 1) acc += __shfl_xor(acc, off);
    __shared__ double ls[4];
    if ((tid & 63) == 0) ls[tid >> 6] = acc;
    __syncthreads();
    if (tid == 0) stats[slot] = ls[0] + ls[1] + ls[2] + ls[3];
}

// block-level sum/sumsq of v[CH] (node-major layout) -> partial[blk*16+...]
__device__ __forceinline__ void block_stats_accum(const float v[CH], float* __restrict__ partial) {
    __shared__ float ls[4][2 * CH];
    int tid = threadIdx.x;
#pragma unroll
    for (int c = 0; c < CH; c++) {
        float s = v[c], q = v[c] * v[c];
#pragma unroll
        for (int off = 32; off; off >>= 1) {
            s += __shfl_xor(s, off);
            q += __shfl_xor(q, off);
        }
        if ((tid & 63) == 0) {
            ls[tid >> 6][c] = s;
            ls[tid >> 6][CH + c] = q;
        }
    }
    __syncthreads();
    if (tid < 2 * CH)
        partial[(size_t)blockIdx.x * 2 * CH + tid] =
            ls[0][tid] + ls[1][tid] + ls[2][tid] + ls[3][tid];
}

// ---------------- embed: stats on raw emb, store hsc = dinv * emb ----------------
__global__ void k_embed(const int* __restrict__ x, const float* __restrict__ emb,
                        const float* __restrict__ dinv,
                        float* __restrict__ hsc, float* __restrict__ partial) {
    int i = blockIdx.x * 256 + threadIdx.x;
    float v[CH];
    if (i < NN) {
        int t = x[i];
#pragma unroll
        for (int c = 0; c < CH; c++) v[c] = emb[t * CH + c];
        float d = dinv[i];
        float4* hp = (float4*)(hsc + (size_t)i * CH);
        hp[0] = make_float4(v[0] * d, v[1] * d, v[2] * d, v[3] * d);
        hp[1] = make_float4(v[4] * d, v[5] * d, v[6] * d, v[7] * d);
    } else {
#pragma unroll
        for (int c = 0; c < CH; c++) v[c] = 0.0f;
    }
    block_stats_accum(v, partial);
}

// ================= fused conv layer (see R7/R8 derivation) =================
__device__ __forceinline__ float conv_val(const int* __restrict__ rowptr,
                                          const int* __restrict__ csr,
                                          const float* __restrict__ dinv,
                                          const float* __restrict__ dsq,
                                          const float* __restrict__ S1,
                                          const float* __restrict__ hsc_in,
                                          const float* sW, const float* sScale,
                                          const float* sShift, const float* sBias,
                                          int t, int node, int c) {
    int beg = rowptr[node], end = rowptr[node + 1];
    double acc0 = 0.0, acc1 = 0.0;
    int e = beg;
    for (; e + 3 < end; e += 4) {
        int s0 = __builtin_nontemporal_load(csr + e);
        int s1 = __builtin_nontemporal_load(csr + e + 1);
        int s2 = __builtin_nontemporal_load(csr + e + 2);
        int s3 = __builtin_nontemporal_load(csr + e + 3);
        acc0 += (double)hsc_in[(size_t)s0 * CH + c] + (double)hsc_in[(size_t)s1 * CH + c];
        acc1 += (double)hsc_in[(size_t)s2 * CH + c] + (double)hsc_in[(size_t)s3 * CH + c];
    }
    for (; e < end; e++)
        acc0 += (double)hsc_in[(size_t)__builtin_nontemporal_load(csr + e) * CH + c];
    float self = hsc_in[t];
    float pre = (float)(acc0 + acc1 + (double)self);
    float d = dinv[node];
    float s1tot = S1[node] + d;
    float pc = pre * sScale[c] + s1tot * sShift[c];
    int base = (threadIdx.x & 63) & ~7;
    float o = 0.0f;
#pragma unroll
    for (int k = 0; k < 8; k++) o += __shfl(pc, base + k) * sW[k * CH + c];
    return self * dsq[node] + sBias[c] + d * o;
}

__device__ __forceinline__ void load_layer_params(const double* __restrict__ stats,
                                                  const float* __restrict__ gamma,
                                                  const float* __restrict__ beta,
                                                  const float* __restrict__ W,
                                                  const float* __restrict__ bias,
                                                  float* sW, float* sScale,
                                                  float* sShift, float* sBias) {
    int tid = threadIdx.x;
    if (tid < CH * CH) sW[tid] = W[tid];
    if (tid < CH) {
        double mu = stats[tid] * (1.0 / NN);
        double var = stats[CH + tid] * (1.0 / NN) - mu * mu;
        float sc = gamma[tid] * rsqrtf((float)var + BEPS);
        sScale[tid] = sc;
        sShift[tid] = beta[tid] - (float)mu * sc;
        sBias[tid] = bias[tid];
    }
    __syncthreads();
}

__global__ void __launch_bounds__(256) k_gconv(const int* __restrict__ rowptr,
                                               const int* __restrict__ csr,
                                               const float* __restrict__ dinv,
                                               const float* __restrict__ dsq,
                                               const float* __restrict__ S1,
                                               const double* __restrict__ stats,
                                               const float* __restrict__ gamma,
                                               const float* __restrict__ beta,
                                               const float* __restrict__ W,
                                               const float* __restrict__ bias,
                                               const float* __restrict__ hsc_in,
                                               float* __restrict__ hsc_out,
                                               float* __restrict__ partial) {
    __shared__ float sW[CH * CH], sScale[CH], sShift[CH], sBias[CH];
    load_layer_params(stats, gamma, beta, W, bias, sW, sScale, sShift, sBias);
    int t = blockIdx.x * 256 + threadIdx.x;
    int node = t >> 3, c = t & 7;
    float val = conv_val(rowptr, csr, dinv, dsq, S1, hsc_in, sW, sScale, sShift, sBias,
                         t, node, c);
    float v = fmaxf(val, 0.0f);
    hsc_out[t] = v * dinv[node];
    float s = v, q = v * v;
#pragma unroll
    for (int off = 8; off < 64; off <<= 1) {
        s += __shfl_xor(s, off);
        q += __shfl_xor(q, off);
    }
    __shared__ float ls[4][2 * CH];
    int lane = threadIdx.x & 63, wid = threadIdx.x >> 6;
    if (lane < CH) { ls[wid][lane] = s; ls[wid][CH + lane] = q; }
    __syncthreads();
    if (threadIdx.x < 2 * CH)
        partial[(size_t)blockIdx.x * 2 * CH + threadIdx.x] =
            ls[0][threadIdx.x] + ls[1][threadIdx.x] + ls[2][threadIdx.x] + ls[3][threadIdx.x];
}

// ---------------- last layer: fused conv + relu + pool (f64 atomics) ----------------
__global__ void __launch_bounds__(256) k_gpool(const int* __restrict__ rowptr,
                                               const int* __restrict__ csr,
                                               const float* __restrict__ dinv,
                                               const float* __restrict__ dsq,
                                               const float* __restrict__ S1,
                                               const double* __restrict__ stats,
                                               const float* __restrict__ gamma,
                                               const float* __restrict__ beta,
                                               const float* __restrict__ W,
                                               const float* __restrict__ bias,
                                               const float* __restrict__ hsc_in,
                                               const int* __restrict__ batch,
                                               double* __restrict__ pooled) {
    __shared__ float sW[CH * CH], sScale[CH], sShift[CH], sBias[CH];
    load_layer_params(stats, gamma, beta, W, bias, sW, sScale, sShift, sBias);
    int t = blockIdx.x * 256 + threadIdx.x;
    int node = t >> 3, c = t & 7;
    float val = conv_val(rowptr, csr, dinv, dsq, S1, hsc_in, sW, sScale, sShift, sBias,
                         t, node, c);
    atomicAdd(&pooled[(size_t)batch[node] * CH + c], (double)fmaxf(val, 0.0f));
}

// ---------------- per-graph MLP ----------------
__global__ void k_mlp(const double* __restrict__ pooled, const float* __restrict__ hid_w,
                      const float* __restrict__ hid_b, const float* __restrict__ out_w,
                      const float* __restrict__ out_b, float* __restrict__ out) {
    int g = blockIdx.x;
    int j = threadIdx.x;  // 128 threads
    __shared__ float sp[CH];
    __shared__ float part[2];
    if (j < CH) sp[j] = (float)pooled[(size_t)g * CH + j];
    __syncthreads();
    float acc = hid_b[j];
#pragma unroll
    for (int c = 0; c < CH; c++) acc += sp[c] * hid_w[c * HID + j];
    acc = fmaxf(acc, 0.0f) * out_w[j];
#pragma unroll
    for (int off = 32; off; off >>= 1) acc += __shfl_xor(acc, off);
    if ((j & 63) == 0) part[j >> 6] = acc;
    __syncthreads();
    if (j == 0) out[g] = part[0] + part[1] + out_b[0];
}

extern "C" void kernel_launch(void* const* d_in, const int* in_sizes, int n_in,
                              void* d_out, int out_size, void* d_ws, size_t ws_size,
                              hipStream_t stream) {
    const int* x = (const int*)d_in[0];
    const int* ei = (const int*)d_in[1];
    const int* srcp = ei;             // edge_index[0]
    const int* dstp = ei + NE;        // edge_index[1]
    const int* batch = (const int*)d_in[2];
    const float* emb = (const float*)d_in[3];
    const float* gamma = (const float*)d_in[4];
    const float* beta = (const float*)d_in[5];
    const float* convw = (const float*)d_in[6];
    const float* convb = (const float*)d_in[7];
    const float* hid_w = (const float*)d_in[8];
    const float* hid_b = (const float*)d_in[9];
    const float* out_w = (const float*)d_in[10];
    const float* out_b = (const float*)d_in[11];
    float* out = (float*)d_out;

    char* ws = (char*)d_ws;
    size_t off = 0;
    int*   hist    = (int*)(ws + off);   off = alignup(off + (size_t)NN * 4, 256);
    int*   cursor  = (int*)(ws + off);   off = alignup(off + (size_t)NN * 4, 256);
    int*   rowptr  = (int*)(ws + off);   off = alignup(off + ((size_t)NN + 1) * 4, 256);
    float* dinv    = (float*)(ws + off); off = alignup(off + (size_t)NN * 4, 256);
    float* dsq     = (float*)(ws + off); off = alignup(off + (size_t)NN * 4, 256);
    float* S1      = (float*)(ws + off); off = alignup(off + (size_t)NN * 4, 256);
    int*   bsum    = (int*)(ws + off);   off = alignup(off + 512 * 4, 256);
    int*   wcur    = (int*)(ws + off);   off = alignup(off + NWIN2 * 4, 256);
    int*   csr     = (int*)(ws + off);   off = alignup(off + (size_t)NE * 4, 256);
    double* pooled = (double*)(ws + off); off = alignup(off + (size_t)NG * CH * 8, 256);
    float* partial = (float*)(ws + off); off = alignup(off + (size_t)NBLK2 * 2 * CH * 4, 256);
    double* stats  = (double*)(ws + off); off = alignup(off + 2 * CH * 8, 256);
    // union region: bucket (build-time) overlaps hA/hB (layer-time; written after build)
    unsigned int* bucket = (unsigned int*)(ws + off);
    float* hA      = (float*)(ws + off); 
    float* hB      = (float*)(ws + off + alignup((size_t)NN * CH * 4, 256));

    const int B = 256;

    k_init<<<NBLK, B, 0, stream>>>(hist, wcur, pooled);
    k_part<<<NPBLK, B, 0, stream>>>(srcp, dstp, wcur, bucket);
    k_histb<<<NWBLK, B, 0, stream>>>(wcur, bucket, hist);
    k_scan1<<<NB_SCAN, B, 0, stream>>>(hist, bsum);
    k_scan2<<<1, 512, 0, stream>>>(bsum);
    k_scan3<<<NB_SCAN, B, 0, stream>>>(hist, bsum, rowptr, cursor, dinv, dsq);
    k_fillb<<<NWBLK, B, 0, stream>>>(wcur, bucket, cursor, csr);
    k_s1<<<NBLK, B, 0, stream>>>(rowptr, csr, dinv, S1);
    // ---- bucket dead from here; hA/hB live ----
    k_embed<<<NBLK, B, 0, stream>>>(x, emb, dinv, hA, partial);
    k_rstats<<<16, 256, 0, stream>>>(partial, NBLK, stats);

    float* hc = hA;
    float* hn = hB;
    for (int i = 0; i < NCONV; i++) {
        if (i < NCONV - 1) {
            k_gconv<<<NBLK2, B, 0, stream>>>(rowptr, csr, dinv, dsq, S1, stats,
                                             gamma + i * CH, beta + i * CH,
                                             convw + i * CH * CH, convb + i * CH,
                                             hc, hn, partial);
            k_rstats<<<16, 256, 0, stream>>>(partial, NBLK2, stats);
            float* tmp = hc; hc = hn; hn = tmp;
        } else {
            k_gpool<<<NBLK2, B, 0, stream>>>(rowptr, csr, dinv, dsq, S1, stats,
                                             gamma + i * CH, beta + i * CH,
                                             convw + i * CH * CH, convb + i * CH,
                                             hc, batch, pooled);
        }
    }
    k_mlp<<<NG, HID, 0, stream>>>(pooled, hid_w, hid_b, out_w, out_b, out);
}

// Round 10
// 1548.460 us; speedup vs baseline: 1.5156x; 1.5156x over previous
//
#include <hip/hip_runtime.h>

#define NN 500000
#define NE 8000000
#define NG 5000
#define CH 8
#define NCONV 8
#define HID 128
#define BEPS 1e-5f

#define NBLK 1954                            // (NN+255)/256  (node-major blocks)
#define NBLK2 15625                          // NN*CH/256     (thread-per-(node,c) blocks, exact)

// ---- LDS counting-sort CSR build ----
#define NWIN 512                             // windows
#define WNODE 977                            // nodes/window; 977*512 = 500224 >= NN
#define WCAP 18432                           // bucket capacity (mean 15625, +18%)
#define PCHUNK 16384                         // edges per partition block
#define NPBLK ((NE + PCHUNK - 1) / PCHUNK)   // 489

static inline size_t alignup(size_t v, size_t a) { return (v + a - 1) / a * a; }

// ---------------- init: zero wcur + pooled(f64) ----------------
__global__ void k_init(int* __restrict__ wcur, double* __restrict__ pooled) {
    int i = blockIdx.x * 256 + threadIdx.x;
    if (i < NWIN) wcur[i] = 0;
    if (i < NG * CH) pooled[i] = 0.0;
}

// ---------------- partition: edges -> 512 window buckets, packed (dloc<<19)|src ----------------
__global__ void __launch_bounds__(1024) k_part(const int* __restrict__ src,
                                               const int* __restrict__ dst,
                                               int* __restrict__ wcur,
                                               unsigned int* __restrict__ bucket) {
    __shared__ int cnt[NWIN], base[NWIN], lcur[NWIN];
    int tid = threadIdx.x;
    for (int i = tid; i < NWIN; i += 1024) cnt[i] = 0;
    __syncthreads();
    int start = blockIdx.x * PCHUNK;
#pragma unroll
    for (int k = 0; k < PCHUNK / 1024; k++) {
        int e = start + k * 1024 + tid;
        if (e < NE) atomicAdd(&cnt[dst[e] / WNODE], 1);
    }
    __syncthreads();
    for (int i = tid; i < NWIN; i += 1024) {
        base[i] = atomicAdd(&wcur[i], cnt[i]);   // one reservation per window per block
        lcur[i] = 0;
    }
    __syncthreads();
#pragma unroll
    for (int k = 0; k < PCHUNK / 1024; k++) {
        int e = start + k * 1024 + tid;
        if (e < NE) {
            int d = dst[e];
            int s = src[e];
            int w = d / WNODE;
            int p = base[w] + atomicAdd(&lcur[w], 1);
            if (p < WCAP)
                bucket[(size_t)w * WCAP + p] = ((unsigned)(d - w * WNODE) << 19) | (unsigned)s;
        }
    }
}

// ---------------- scan window totals -> wbase; rowptr[NN]=NE ----------------
__global__ void k_wscan(const int* __restrict__ wcur, int* __restrict__ wbase,
                        int* __restrict__ rowptr) {
    __shared__ int s[NWIN];
    int tid = threadIdx.x;   // 512
    int v = wcur[tid]; if (v > WCAP) v = WCAP;
    s[tid] = v;
    __syncthreads();
    for (int off = 1; off < NWIN; off <<= 1) {
        int t = (tid >= off) ? s[tid - off] : 0;
        __syncthreads();
        s[tid] += t;
        __syncthreads();
    }
    wbase[tid] = s[tid] - v;  // exclusive
    if (tid == NWIN - 1) rowptr[NN] = s[tid];
}

// ---------------- per-window LDS counting sort: hist+scan+scatter in LDS, csr written SEQUENTIALLY --
__global__ void __launch_bounds__(1024) k_sortwin(const int* __restrict__ wcur,
                                                  const int* __restrict__ wbase,
                                                  const unsigned int* __restrict__ bucket,
                                                  int* __restrict__ rowptr,
                                                  float* __restrict__ dinv,
                                                  float* __restrict__ dsq,
                                                  int* __restrict__ csr) {
    __shared__ int lh[WNODE];            // counts -> cursor
    __shared__ unsigned int sout[WCAP];  // sorted src (72KB)
    __shared__ int wsums[16];
    int w = blockIdx.x, tid = threadIdx.x;
    int n = wcur[w]; if (n > WCAP) n = WCAP;
    const unsigned int* bp = bucket + (size_t)w * WCAP;
    for (int i = tid; i < WNODE; i += 1024) lh[i] = 0;
    __syncthreads();
    // pass 1: window-local histogram (LDS atomics)
    for (int e = tid; e < n; e += 1024)
        atomicAdd(&lh[__builtin_nontemporal_load(bp + e) >> 19], 1);
    __syncthreads();
    // exclusive scan of lh[0..WNODE): 1 elem/thread
    int gbase = w * WNODE;
    int nnode = NN - gbase; if (nnode > WNODE) nnode = WNODE;
    int v = (tid < WNODE) ? lh[tid] : 0;
    int lane = tid & 63, wid = tid >> 6;
    int incl = v;
#pragma unroll
    for (int off = 1; off < 64; off <<= 1) {
        int t = __shfl_up(incl, off);
        if (lane >= off) incl += t;
    }
    if (lane == 63) wsums[wid] = incl;
    __syncthreads();
    if (tid == 0) {
        int run = 0;
#pragma unroll
        for (int i = 0; i < 16; i++) { int t = wsums[i]; wsums[i] = run; run += t; }
    }
    __syncthreads();
    int excl = incl - v + wsums[wid];
    if (tid < nnode) {
        rowptr[gbase + tid] = wbase[w] + excl;
        float deg = (float)(v + 1);      // +1 self-loop
        dinv[gbase + tid] = rsqrtf(deg);
        dsq[gbase + tid] = sqrtf(deg);
    }
    __syncthreads();
    if (tid < WNODE) lh[tid] = excl;     // local cursor
    __syncthreads();
    // pass 2: scatter into LDS
    for (int e = tid; e < n; e += 1024) {
        unsigned int p = __builtin_nontemporal_load(bp + e);
        int pos = atomicAdd(&lh[p >> 19], 1);
        sout[pos] = p & 0x7FFFFu;
    }
    __syncthreads();
    // sequential coalesced write-out
    int cb = wbase[w];
    for (int e = tid; e < n; e += 1024)
        csr[cb + e] = (int)sout[e];
}

// ---------------- one-time: S1[n] = sum_{s in N(n)} dinv[s]  (f64 -> stable) ----------------
__global__ void k_s1(const int* __restrict__ rowptr, const int* __restrict__ csr,
                     const float* __restrict__ dinv, float* __restrict__ S1) {
    int n = blockIdx.x * 256 + threadIdx.x;
    if (n >= NN) return;
    int beg = rowptr[n], end = rowptr[n + 1];
    double a = 0.0;
    for (int e = beg; e < end; e++) a += (double)dinv[__builtin_nontemporal_load(csr + e)];
    S1[n] = (float)a;
}

// ---------------- reduce partials -> stats[16] (f64); block b owns slot b ----------------
__global__ void k_rstats(const float* __restrict__ partial, int nblk, double* __restrict__ stats) {
    int slot = blockIdx.x;     // 0..15
    int tid = threadIdx.x;     // 256
    double acc = 0.0;
    for (int j = tid; j < nblk; j += 256) acc += (double)partial[(size_t)j * 16 + slot];
#pragma unroll
    for (int off = 32; off; off >>= 1) acc += __shfl_xor(acc, off);
    __shared__ double ls[4];
    if ((tid & 63) == 0) ls[tid >> 6] = acc;
    __syncthreads();
    if (tid == 0) stats[slot] = ls[0] + ls[1] + ls[2] + ls[3];
}

// block-level sum/sumsq of v[CH] (node-major layout) -> partial[blk*16+...]
__device__ __forceinline__ void block_stats_accum(const float v[CH], float* __restrict__ partial) {
    __shared__ float ls[4][2 * CH];
    int tid = threadIdx.x;
#pragma unroll
    for (int c = 0; c < CH; c++) {
        float s = v[c], q = v[c] * v[c];
#pragma unroll
        for (int off = 32; off; off >>= 1) {
            s += __shfl_xor(s, off);
            q += __shfl_xor(q, off);
        }
        if ((tid & 63) == 0) {
            ls[tid >> 6][c] = s;
            ls[tid >> 6][CH + c] = q;
        }
    }
    __syncthreads();
    if (tid < 2 * CH)
        partial[(size_t)blockIdx.x * 2 * CH + tid] =
            ls[0][tid] + ls[1][tid] + ls[2][tid] + ls[3][tid];
}

// ---------------- embed: stats on raw emb, store hsc = dinv * emb ----------------
__global__ void k_embed(const int* __restrict__ x, const float* __restrict__ emb,
                        const float* __restrict__ dinv,
                        float* __restrict__ hsc, float* __restrict__ partial) {
    int i = blockIdx.x * 256 + threadIdx.x;
    float v[CH];
    if (i < NN) {
        int t = x[i];
#pragma unroll
        for (int c = 0; c < CH; c++) v[c] = emb[t * CH + c];
        float d = dinv[i];
        float4* hp = (float4*)(hsc + (size_t)i * CH);
        hp[0] = make_float4(v[0] * d, v[1] * d, v[2] * d, v[3] * d);
        hp[1] = make_float4(v[4] * d, v[5] * d, v[6] * d, v[7] * d);
    } else {
#pragma unroll
        for (int c = 0; c < CH; c++) v[c] = 0.0f;
    }
    block_stats_accum(v, partial);
}

// ================= fused conv layer (R7/R8 derivation) =================
__device__ __forceinline__ float conv_val(const int* __restrict__ rowptr,
                                          const int* __restrict__ csr,
                                          const float* __restrict__ dinv,
                                          const float* __restrict__ dsq,
                                          const float* __restrict__ S1,
                                          const float* __restrict__ hsc_in,
                                          const float* sW, const float* sScale,
                                          const float* sShift, const float* sBias,
                                          int t, int node, int c) {
    int beg = rowptr[node], end = rowptr[node + 1];
    double acc0 = 0.0, acc1 = 0.0;
    int e = beg;
    for (; e + 3 < end; e += 4) {
        int s0 = __builtin_nontemporal_load(csr + e);
        int s1 = __builtin_nontemporal_load(csr + e + 1);
        int s2 = __builtin_nontemporal_load(csr + e + 2);
        int s3 = __builtin_nontemporal_load(csr + e + 3);
        acc0 += (double)hsc_in[(size_t)s0 * CH + c] + (double)hsc_in[(size_t)s1 * CH + c];
        acc1 += (double)hsc_in[(size_t)s2 * CH + c] + (double)hsc_in[(size_t)s3 * CH + c];
    }
    for (; e < end; e++)
        acc0 += (double)hsc_in[(size_t)__builtin_nontemporal_load(csr + e) * CH + c];
    float self = hsc_in[t];
    float pre = (float)(acc0 + acc1 + (double)self);
    float d = dinv[node];
    float s1tot = S1[node] + d;
    float pc = pre * sScale[c] + s1tot * sShift[c];
    int base = (threadIdx.x & 63) & ~7;
    float o = 0.0f;
#pragma unroll
    for (int k = 0; k < 8; k++) o += __shfl(pc, base + k) * sW[k * CH + c];
    return self * dsq[node] + sBias[c] + d * o;
}

__device__ __forceinline__ void load_layer_params(const double* __restrict__ stats,
                                                  const float* __restrict__ gamma,
                                                  const float* __restrict__ beta,
                                                  const float* __restrict__ W,
                                                  const float* __restrict__ bias,
                                                  float* sW, float* sScale,
                                                  float* sShift, float* sBias) {
    int tid = threadIdx.x;
    if (tid < CH * CH) sW[tid] = W[tid];
    if (tid < CH) {
        double mu = stats[tid] * (1.0 / NN);
        double var = stats[CH + tid] * (1.0 / NN) - mu * mu;
        float sc = gamma[tid] * rsqrtf((float)var + BEPS);
        sScale[tid] = sc;
        sShift[tid] = beta[tid] - (float)mu * sc;
        sBias[tid] = bias[tid];
    }
    __syncthreads();
}

__global__ void __launch_bounds__(256) k_gconv(const int* __restrict__ rowptr,
                                               const int* __restrict__ csr,
                                               const float* __restrict__ dinv,
                                               const float* __restrict__ dsq,
                                               const float* __restrict__ S1,
                                               const double* __restrict__ stats,
                                               const float* __restrict__ gamma,
                                               const float* __restrict__ beta,
                                               const float* __restrict__ W,
                                               const float* __restrict__ bias,
                                               const float* __restrict__ hsc_in,
                                               float* __restrict__ hsc_out,
                                               float* __restrict__ partial) {
    __shared__ float sW[CH * CH], sScale[CH], sShift[CH], sBias[CH];
    load_layer_params(stats, gamma, beta, W, bias, sW, sScale, sShift, sBias);
    int t = blockIdx.x * 256 + threadIdx.x;
    int node = t >> 3, c = t & 7;
    float val = conv_val(rowptr, csr, dinv, dsq, S1, hsc_in, sW, sScale, sShift, sBias,
                         t, node, c);
    float v = fmaxf(val, 0.0f);
    hsc_out[t] = v * dinv[node];
    float s = v, q = v * v;
#pragma unroll
    for (int off = 8; off < 64; off <<= 1) {
        s += __shfl_xor(s, off);
        q += __shfl_xor(q, off);
    }
    __shared__ float ls[4][2 * CH];
    int lane = threadIdx.x & 63, wid = threadIdx.x >> 6;
    if (lane < CH) { ls[wid][lane] = s; ls[wid][CH + lane] = q; }
    __syncthreads();
    if (threadIdx.x < 2 * CH)
        partial[(size_t)blockIdx.x * 2 * CH + threadIdx.x] =
            ls[0][threadIdx.x] + ls[1][threadIdx.x] + ls[2][threadIdx.x] + ls[3][threadIdx.x];
}

// ---------------- last layer: fused conv + relu + pool (f64 atomics) ----------------
__global__ void __launch_bounds__(256) k_gpool(const int* __restrict__ rowptr,
                                               const int* __restrict__ csr,
                                               const float* __restrict__ dinv,
                                               const float* __restrict__ dsq,
                                               const float* __restrict__ S1,
                                               const double* __restrict__ stats,
                                               const float* __restrict__ gamma,
                                               const float* __restrict__ beta,
                                               const float* __restrict__ W,
                                               const float* __restrict__ bias,
                                               const float* __restrict__ hsc_in,
                                               const int* __restrict__ batch,
                                               double* __restrict__ pooled) {
    __shared__ float sW[CH * CH], sScale[CH], sShift[CH], sBias[CH];
    load_layer_params(stats, gamma, beta, W, bias, sW, sScale, sShift, sBias);
    int t = blockIdx.x * 256 + threadIdx.x;
    int node = t >> 3, c = t & 7;
    float val = conv_val(rowptr, csr, dinv, dsq, S1, hsc_in, sW, sScale, sShift, sBias,
                         t, node, c);
    atomicAdd(&pooled[(size_t)batch[node] * CH + c], (double)fmaxf(val, 0.0f));
}

// ---------------- per-graph MLP ----------------
__global__ void k_mlp(const double* __restrict__ pooled, const float* __restrict__ hid_w,
                      const float* __restrict__ hid_b, const float* __restrict__ out_w,
                      const float* __restrict__ out_b, float* __restrict__ out) {
    int g = blockIdx.x;
    int j = threadIdx.x;  // 128 threads
    __shared__ float sp[CH];
    __shared__ float part[2];
    if (j < CH) sp[j] = (float)pooled[(size_t)g * CH + j];
    __syncthreads();
    float acc = hid_b[j];
#pragma unroll
    for (int c = 0; c < CH; c++) acc += sp[c] * hid_w[c * HID + j];
    acc = fmaxf(acc, 0.0f) * out_w[j];
#pragma unroll
    for (int off = 32; off; off >>= 1) acc += __shfl_xor(acc, off);
    if ((j & 63) == 0) part[j >> 6] = acc;
    __syncthreads();
    if (j == 0) out[g] = part[0] + part[1] + out_b[0];
}

extern "C" void kernel_launch(void* const* d_in, const int* in_sizes, int n_in,
                              void* d_out, int out_size, void* d_ws, size_t ws_size,
                              hipStream_t stream) {
    const int* x = (const int*)d_in[0];
    const int* ei = (const int*)d_in[1];
    const int* srcp = ei;             // edge_index[0]
    const int* dstp = ei + NE;        // edge_index[1]
    const int* batch = (const int*)d_in[2];
    const float* emb = (const float*)d_in[3];
    const float* gamma = (const float*)d_in[4];
    const float* beta = (const float*)d_in[5];
    const float* convw = (const float*)d_in[6];
    const float* convb = (const float*)d_in[7];
    const float* hid_w = (const float*)d_in[8];
    const float* hid_b = (const float*)d_in[9];
    const float* out_w = (const float*)d_in[10];
    const float* out_b = (const float*)d_in[11];
    float* out = (float*)d_out;

    char* ws = (char*)d_ws;
    size_t off = 0;
    int*   rowptr  = (int*)(ws + off);   off = alignup(off + ((size_t)NN + 1) * 4, 256);
    float* dinv    = (float*)(ws + off); off = alignup(off + (size_t)NN * 4, 256);
    float* dsq     = (float*)(ws + off); off = alignup(off + (size_t)NN * 4, 256);
    float* S1      = (float*)(ws + off); off = alignup(off + (size_t)NN * 4, 256);
    int*   wcur    = (int*)(ws + off);   off = alignup(off + NWIN * 4, 256);
    int*   wbase   = (int*)(ws + off);   off = alignup(off + NWIN * 4, 256);
    int*   csr     = (int*)(ws + off);   off = alignup(off + (size_t)NE * 4, 256);
    double* pooled = (double*)(ws + off); off = alignup(off + (size_t)NG * CH * 8, 256);
    float* partial = (float*)(ws + off); off = alignup(off + (size_t)NBLK2 * 2 * CH * 4, 256);
    double* stats  = (double*)(ws + off); off = alignup(off + 2 * CH * 8, 256);
    // union region: bucket (build-time) overlaps hA/hB (layer-time; written after build)
    unsigned int* bucket = (unsigned int*)(ws + off);   // 512*18432*4 = 37.75MB
    float* hA      = (float*)(ws + off);
    float* hB      = (float*)(ws + off + alignup((size_t)NN * CH * 4, 256));

    const int B = 256;

    k_init<<<(NG * CH + B - 1) / B, B, 0, stream>>>(wcur, pooled);
    k_part<<<NPBLK, 1024, 0, stream>>>(srcp, dstp, wcur, bucket);
    k_wscan<<<1, NWIN, 0, stream>>>(wcur, wbase, rowptr);
    k_sortwin<<<NWIN, 1024, 0, stream>>>(wcur, wbase, bucket, rowptr, dinv, dsq, csr);
    k_s1<<<NBLK, B, 0, stream>>>(rowptr, csr, dinv, S1);
    // ---- bucket dead from here; hA/hB live ----
    k_embed<<<NBLK, B, 0, stream>>>(x, emb, dinv, hA, partial);
    k_rstats<<<16, 256, 0, stream>>>(partial, NBLK, stats);

    float* hc = hA;
    float* hn = hB;
    for (int i = 0; i < NCONV; i++) {
        if (i < NCONV - 1) {
            k_gconv<<<NBLK2, B, 0, stream>>>(rowptr, csr, dinv, dsq, S1, stats,
                                             gamma + i * CH, beta + i * CH,
                                             convw + i * CH * CH, convb + i * CH,
                                             hc, hn, partial);
            k_rstats<<<16, 256, 0, stream>>>(partial, NBLK2, stats);
            float* tmp = hc; hc = hn; hn = tmp;
        } else {
            k_gpool<<<NBLK2, B, 0, stream>>>(rowptr, csr, dinv, dsq, S1, stats,
                                             gamma + i * CH, beta + i * CH,
                                             convw + i * CH * CH, convb + i * CH,
                                             hc, batch, pooled);
        }
    }
    k_mlp<<<NG, HID, 0, stream>>>(pooled, hid_w, hid_b, out_w, out_b, out);
}

// Round 11
// 1508.706 us; speedup vs baseline: 1.5556x; 1.0263x over previous
//
#include <hip/hip_runtime.h>

#define NN 500000
#define NE 8000000
#define NG 5000
#define CH 8
#define NCONV 8
#define HID 128
#define BEPS 1e-5f

#define NBLK 1954                            // (NN+255)/256  (node-major blocks)
#define NPAIR 250000                         // node pairs
#define NBLKP 7813                           // (NPAIR*CH+255)/256

// ---- LDS counting-sort CSR build ----
#define NWIN 512                             // windows
#define WNODE 977                            // nodes/window; 977*512 = 500224 >= NN
#define WCAP 18432                           // bucket capacity (mean 15625, +18%)
#define PCHUNK 16384                         // edges per partition block
#define NPBLK ((NE + PCHUNK - 1) / PCHUNK)   // 489

static inline size_t alignup(size_t v, size_t a) { return (v + a - 1) / a * a; }

// ---------------- init: zero wcur + pooled(f64) ----------------
__global__ void k_init(int* __restrict__ wcur, double* __restrict__ pooled) {
    int i = blockIdx.x * 256 + threadIdx.x;
    if (i < NWIN) wcur[i] = 0;
    if (i < NG * CH) pooled[i] = 0.0;
}

// ---------------- partition: edges -> 512 window buckets, packed (dloc<<19)|src ----------------
__global__ void __launch_bounds__(1024) k_part(const int* __restrict__ src,
                                               const int* __restrict__ dst,
                                               int* __restrict__ wcur,
                                               unsigned int* __restrict__ bucket) {
    __shared__ int cnt[NWIN], base[NWIN], lcur[NWIN];
    int tid = threadIdx.x;
    for (int i = tid; i < NWIN; i += 1024) cnt[i] = 0;
    __syncthreads();
    int start = blockIdx.x * PCHUNK;
#pragma unroll
    for (int k = 0; k < PCHUNK / 1024; k++) {
        int e = start + k * 1024 + tid;
        if (e < NE) atomicAdd(&cnt[dst[e] / WNODE], 1);
    }
    __syncthreads();
    for (int i = tid; i < NWIN; i += 1024) {
        base[i] = atomicAdd(&wcur[i], cnt[i]);   // one reservation per window per block
        lcur[i] = 0;
    }
    __syncthreads();
#pragma unroll
    for (int k = 0; k < PCHUNK / 1024; k++) {
        int e = start + k * 1024 + tid;
        if (e < NE) {
            int d = dst[e];
            int s = src[e];
            int w = d / WNODE;
            int p = base[w] + atomicAdd(&lcur[w], 1);
            if (p < WCAP)
                bucket[(size_t)w * WCAP + p] = ((unsigned)(d - w * WNODE) << 19) | (unsigned)s;
        }
    }
}

// ---------------- scan window totals -> wbase; rowptr[NN]=NE ----------------
__global__ void k_wscan(const int* __restrict__ wcur, int* __restrict__ wbase,
                        int* __restrict__ rowptr) {
    __shared__ int s[NWIN];
    int tid = threadIdx.x;   // 512
    int v = wcur[tid]; if (v > WCAP) v = WCAP;
    s[tid] = v;
    __syncthreads();
    for (int off = 1; off < NWIN; off <<= 1) {
        int t = (tid >= off) ? s[tid - off] : 0;
        __syncthreads();
        s[tid] += t;
        __syncthreads();
    }
    wbase[tid] = s[tid] - v;  // exclusive
    if (tid == NWIN - 1) rowptr[NN] = s[tid];
}

// ---------------- per-window LDS counting sort ----------------
__global__ void __launch_bounds__(1024) k_sortwin(const int* __restrict__ wcur,
                                                  const int* __restrict__ wbase,
                                                  const unsigned int* __restrict__ bucket,
                                                  int* __restrict__ rowptr,
                                                  float* __restrict__ dinv,
                                                  float* __restrict__ dsq,
                                                  int* __restrict__ csr) {
    __shared__ int lh[WNODE];            // counts -> cursor
    __shared__ unsigned int sout[WCAP];  // sorted src (72KB)
    __shared__ int wsums[16];
    int w = blockIdx.x, tid = threadIdx.x;
    int n = wcur[w]; if (n > WCAP) n = WCAP;
    const unsigned int* bp = bucket + (size_t)w * WCAP;
    for (int i = tid; i < WNODE; i += 1024) lh[i] = 0;
    __syncthreads();
    for (int e = tid; e < n; e += 1024)
        atomicAdd(&lh[__builtin_nontemporal_load(bp + e) >> 19], 1);
    __syncthreads();
    int gbase = w * WNODE;
    int nnode = NN - gbase; if (nnode > WNODE) nnode = WNODE;
    int v = (tid < WNODE) ? lh[tid] : 0;
    int lane = tid & 63, wid = tid >> 6;
    int incl = v;
#pragma unroll
    for (int off = 1; off < 64; off <<= 1) {
        int t = __shfl_up(incl, off);
        if (lane >= off) incl += t;
    }
    if (lane == 63) wsums[wid] = incl;
    __syncthreads();
    if (tid == 0) {
        int run = 0;
#pragma unroll
        for (int i = 0; i < 16; i++) { int t = wsums[i]; wsums[i] = run; run += t; }
    }
    __syncthreads();
    int excl = incl - v + wsums[wid];
    if (tid < nnode) {
        rowptr[gbase + tid] = wbase[w] + excl;
        float deg = (float)(v + 1);      // +1 self-loop
        dinv[gbase + tid] = rsqrtf(deg);
        dsq[gbase + tid] = sqrtf(deg);
    }
    __syncthreads();
    if (tid < WNODE) lh[tid] = excl;     // local cursor
    __syncthreads();
    for (int e = tid; e < n; e += 1024) {
        unsigned int p = __builtin_nontemporal_load(bp + e);
        int pos = atomicAdd(&lh[p >> 19], 1);
        sout[pos] = p & 0x7FFFFu;
    }
    __syncthreads();
    int cb = wbase[w];
    for (int e = tid; e < n; e += 1024)
        csr[cb + e] = (int)sout[e];
}

// ---------------- one-time: S1[n] = sum_{s in N(n)} dinv[s]  (f64 -> stable) ----------------
__global__ void k_s1(const int* __restrict__ rowptr, const int* __restrict__ csr,
                     const float* __restrict__ dinv, float* __restrict__ S1) {
    int n = blockIdx.x * 256 + threadIdx.x;
    if (n >= NN) return;
    int beg = rowptr[n], end = rowptr[n + 1];
    double a = 0.0;
    for (int e = beg; e < end; e++) a += (double)dinv[__builtin_nontemporal_load(csr + e)];
    S1[n] = (float)a;
}

// ---------------- reduce partials -> stats[16] (f64); block b owns slot b ----------------
__global__ void k_rstats(const float* __restrict__ partial, int nblk, double* __restrict__ stats) {
    int slot = blockIdx.x;     // 0..15
    int tid = threadIdx.x;     // 256
    double acc = 0.0;
    for (int j = tid; j < nblk; j += 256) acc += (double)partial[(size_t)j * 16 + slot];
#pragma unroll
    for (int off = 32; off; off >>= 1) acc += __shfl_xor(acc, off);
    __shared__ double ls[4];
    if ((tid & 63) == 0) ls[tid >> 6] = acc;
    __syncthreads();
    if (tid == 0) stats[slot] = ls[0] + ls[1] + ls[2] + ls[3];
}

// block-level sum/sumsq of v[CH] (node-major layout) -> partial[blk*16+...]
__device__ __forceinline__ void block_stats_accum(const float v[CH], float* __restrict__ partial) {
    __shared__ float ls[4][2 * CH];
    int tid = threadIdx.x;
#pragma unroll
    for (int c = 0; c < CH; c++) {
        float s = v[c], q = v[c] * v[c];
#pragma unroll
        for (int off = 32; off; off >>= 1) {
            s += __shfl_xor(s, off);
            q += __shfl_xor(q, off);
        }
        if ((tid & 63) == 0) {
            ls[tid >> 6][c] = s;
            ls[tid >> 6][CH + c] = q;
        }
    }
    __syncthreads();
    if (tid < 2 * CH)
        partial[(size_t)blockIdx.x * 2 * CH + tid] =
            ls[0][tid] + ls[1][tid] + ls[2][tid] + ls[3][tid];
}

// ---------------- embed: stats on raw emb, store hsc = dinv * emb ----------------
__global__ void k_embed(const int* __restrict__ x, const float* __restrict__ emb,
                        const float* __restrict__ dinv,
                        float* __restrict__ hsc, float* __restrict__ partial) {
    int i = blockIdx.x * 256 + threadIdx.x;
    float v[CH];
    if (i < NN) {
        int t = x[i];
#pragma unroll
        for (int c = 0; c < CH; c++) v[c] = emb[t * CH + c];
        float d = dinv[i];
        float4* hp = (float4*)(hsc + (size_t)i * CH);
        hp[0] = make_float4(v[0] * d, v[1] * d, v[2] * d, v[3] * d);
        hp[1] = make_float4(v[4] * d, v[5] * d, v[6] * d, v[7] * d);
    } else {
#pragma unroll
        for (int c = 0; c < CH; c++) v[c] = 0.0f;
    }
    block_stats_accum(v, partial);
}

// ================= fused conv layer — 2 nodes/thread for 2x memory-level parallelism =============
__device__ __forceinline__ void load_layer_params(const double* __restrict__ stats,
                                                  const float* __restrict__ gamma,
                                                  const float* __restrict__ beta,
                                                  const float* __restrict__ W,
                                                  const float* __restrict__ bias,
                                                  float* sW, float* sScale,
                                                  float* sShift, float* sBias) {
    int tid = threadIdx.x;
    if (tid < CH * CH) sW[tid] = W[tid];
    if (tid < CH) {
        double mu = stats[tid] * (1.0 / NN);
        double var = stats[CH + tid] * (1.0 / NN) - mu * mu;
        float sc = gamma[tid] * rsqrtf((float)var + BEPS);
        sScale[tid] = sc;
        sShift[tid] = beta[tid] - (float)mu * sc;
        sBias[tid] = bias[tid];
    }
    __syncthreads();
}

// computes post-conv pre-relu values for node pair (n0, n1=n0+1), channel c
__device__ __forceinline__ void conv_val2(const int* __restrict__ rowptr,
                                          const int* __restrict__ csr,
                                          const float* __restrict__ dinv,
                                          const float* __restrict__ dsq,
                                          const float* __restrict__ S1,
                                          const float* __restrict__ hsc_in,
                                          const float* sW, const float* sScale,
                                          const float* sShift, const float* sBias,
                                          int n0, int c, float& val0, float& val1) {
    int n1 = n0 + 1;
    int e0 = rowptr[n0], end0 = rowptr[n0 + 1], end1 = rowptr[n1 + 1];
    int e1 = end0;
    double a00 = 0.0, a01 = 0.0, a10 = 0.0, a11 = 0.0;
    // joint 4-unrolled loop: 8 independent hsc loads in flight
    while (e0 + 3 < end0 && e1 + 3 < end1) {
        int s00 = __builtin_nontemporal_load(csr + e0);
        int s01 = __builtin_nontemporal_load(csr + e0 + 1);
        int s02 = __builtin_nontemporal_load(csr + e0 + 2);
        int s03 = __builtin_nontemporal_load(csr + e0 + 3);
        int s10 = __builtin_nontemporal_load(csr + e1);
        int s11 = __builtin_nontemporal_load(csr + e1 + 1);
        int s12 = __builtin_nontemporal_load(csr + e1 + 2);
        int s13 = __builtin_nontemporal_load(csr + e1 + 3);
        a00 += (double)hsc_in[(size_t)s00 * CH + c] + (double)hsc_in[(size_t)s01 * CH + c];
        a01 += (double)hsc_in[(size_t)s02 * CH + c] + (double)hsc_in[(size_t)s03 * CH + c];
        a10 += (double)hsc_in[(size_t)s10 * CH + c] + (double)hsc_in[(size_t)s11 * CH + c];
        a11 += (double)hsc_in[(size_t)s12 * CH + c] + (double)hsc_in[(size_t)s13 * CH + c];
        e0 += 4; e1 += 4;
    }
    while (e0 + 3 < end0) {
        int s00 = __builtin_nontemporal_load(csr + e0);
        int s01 = __builtin_nontemporal_load(csr + e0 + 1);
        int s02 = __builtin_nontemporal_load(csr + e0 + 2);
        int s03 = __builtin_nontemporal_load(csr + e0 + 3);
        a00 += (double)hsc_in[(size_t)s00 * CH + c] + (double)hsc_in[(size_t)s01 * CH + c];
        a01 += (double)hsc_in[(size_t)s02 * CH + c] + (double)hsc_in[(size_t)s03 * CH + c];
        e0 += 4;
    }
    while (e1 + 3 < end1) {
        int s10 = __builtin_nontemporal_load(csr + e1);
        int s11 = __builtin_nontemporal_load(csr + e1 + 1);
        int s12 = __builtin_nontemporal_load(csr + e1 + 2);
        int s13 = __builtin_nontemporal_load(csr + e1 + 3);
        a10 += (double)hsc_in[(size_t)s10 * CH + c] + (double)hsc_in[(size_t)s11 * CH + c];
        a11 += (double)hsc_in[(size_t)s12 * CH + c] + (double)hsc_in[(size_t)s13 * CH + c];
        e1 += 4;
    }
    for (; e0 < end0; e0++)
        a00 += (double)hsc_in[(size_t)__builtin_nontemporal_load(csr + e0) * CH + c];
    for (; e1 < end1; e1++)
        a10 += (double)hsc_in[(size_t)__builtin_nontemporal_load(csr + e1) * CH + c];

    float self0 = hsc_in[(size_t)n0 * CH + c];
    float self1 = hsc_in[(size_t)n1 * CH + c];
    float pre0 = (float)(a00 + a01 + (double)self0);
    float pre1 = (float)(a10 + a11 + (double)self1);
    float d0 = dinv[n0], d1 = dinv[n1];
    float pc0 = pre0 * sScale[c] + (S1[n0] + d0) * sShift[c];
    float pc1 = pre1 * sScale[c] + (S1[n1] + d1) * sShift[c];
    int base = (threadIdx.x & 63) & ~7;
    float o0 = 0.0f, o1 = 0.0f;
#pragma unroll
    for (int k = 0; k < 8; k++) {
        float wkc = sW[k * CH + c];
        o0 += __shfl(pc0, base + k) * wkc;
        o1 += __shfl(pc1, base + k) * wkc;
    }
    val0 = self0 * dsq[n0] + sBias[c] + d0 * o0;
    val1 = self1 * dsq[n1] + sBias[c] + d1 * o1;
}

__global__ void __launch_bounds__(256) k_gconv(const int* __restrict__ rowptr,
                                               const int* __restrict__ csr,
                                               const float* __restrict__ dinv,
                                               const float* __restrict__ dsq,
                                               const float* __restrict__ S1,
                                               const double* __restrict__ stats,
                                               const float* __restrict__ gamma,
                                               const float* __restrict__ beta,
                                               const float* __restrict__ W,
                                               const float* __restrict__ bias,
                                               const float* __restrict__ hsc_in,
                                               float* __restrict__ hsc_out,
                                               float* __restrict__ partial) {
    __shared__ float sW[CH * CH], sScale[CH], sShift[CH], sBias[CH];
    load_layer_params(stats, gamma, beta, W, bias, sW, sScale, sShift, sBias);
    int t = blockIdx.x * 256 + threadIdx.x;
    int pair = t >> 3, c = t & 7;
    float v0 = 0.0f, v1 = 0.0f;
    if (pair < NPAIR) {
        int n0 = pair * 2;
        float val0, val1;
        conv_val2(rowptr, csr, dinv, dsq, S1, hsc_in, sW, sScale, sShift, sBias,
                  n0, c, val0, val1);
        v0 = fmaxf(val0, 0.0f);
        v1 = fmaxf(val1, 0.0f);
        hsc_out[(size_t)n0 * CH + c] = v0 * dinv[n0];
        hsc_out[(size_t)(n0 + 1) * CH + c] = v1 * dinv[n0 + 1];
    }
    // per-channel block stats over both nodes
    float s = v0 + v1, q = v0 * v0 + v1 * v1;
#pragma unroll
    for (int off = 8; off < 64; off <<= 1) {
        s += __shfl_xor(s, off);
        q += __shfl_xor(q, off);
    }
    __shared__ float ls[4][2 * CH];
    int lane = threadIdx.x & 63, wid = threadIdx.x >> 6;
    if (lane < CH) { ls[wid][lane] = s; ls[wid][CH + lane] = q; }
    __syncthreads();
    if (threadIdx.x < 2 * CH)
        partial[(size_t)blockIdx.x * 2 * CH + threadIdx.x] =
            ls[0][threadIdx.x] + ls[1][threadIdx.x] + ls[2][threadIdx.x] + ls[3][threadIdx.x];
}

// ---------------- last layer: fused conv + relu + pool (f64 atomics) ----------------
__global__ void __launch_bounds__(256) k_gpool(const int* __restrict__ rowptr,
                                               const int* __restrict__ csr,
                                               const float* __restrict__ dinv,
                                               const float* __restrict__ dsq,
                                               const float* __restrict__ S1,
                                               const double* __restrict__ stats,
                                               const float* __restrict__ gamma,
                                               const float* __restrict__ beta,
                                               const float* __restrict__ W,
                                               const float* __restrict__ bias,
                                               const float* __restrict__ hsc_in,
                                               const int* __restrict__ batch,
                                               double* __restrict__ pooled) {
    __shared__ float sW[CH * CH], sScale[CH], sShift[CH], sBias[CH];
    load_layer_params(stats, gamma, beta, W, bias, sW, sScale, sShift, sBias);
    int t = blockIdx.x * 256 + threadIdx.x;
    int pair = t >> 3, c = t & 7;
    if (pair >= NPAIR) return;
    int n0 = pair * 2;
    float val0, val1;
    conv_val2(rowptr, csr, dinv, dsq, S1, hsc_in, sW, sScale, sShift, sBias,
              n0, c, val0, val1);
    atomicAdd(&pooled[(size_t)batch[n0] * CH + c], (double)fmaxf(val0, 0.0f));
    atomicAdd(&pooled[(size_t)batch[n0 + 1] * CH + c], (double)fmaxf(val1, 0.0f));
}

// ---------------- per-graph MLP ----------------
__global__ void k_mlp(const double* __restrict__ pooled, const float* __restrict__ hid_w,
                      const float* __restrict__ hid_b, const float* __restrict__ out_w,
                      const float* __restrict__ out_b, float* __restrict__ out) {
    int g = blockIdx.x;
    int j = threadIdx.x;  // 128 threads
    __shared__ float sp[CH];
    __shared__ float part[2];
    if (j < CH) sp[j] = (float)pooled[(size_t)g * CH + j];
    __syncthreads();
    float acc = hid_b[j];
#pragma unroll
    for (int c = 0; c < CH; c++) acc += sp[c] * hid_w[c * HID + j];
    acc = fmaxf(acc, 0.0f) * out_w[j];
#pragma unroll
    for (int off = 32; off; off >>= 1) acc += __shfl_xor(acc, off);
    if ((j & 63) == 0) part[j >> 6] = acc;
    __syncthreads();
    if (j == 0) out[g] = part[0] + part[1] + out_b[0];
}

extern "C" void kernel_launch(void* const* d_in, const int* in_sizes, int n_in,
                              void* d_out, int out_size, void* d_ws, size_t ws_size,
                              hipStream_t stream) {
    const int* x = (const int*)d_in[0];
    const int* ei = (const int*)d_in[1];
    const int* srcp = ei;             // edge_index[0]
    const int* dstp = ei + NE;        // edge_index[1]
    const int* batch = (const int*)d_in[2];
    const float* emb = (const float*)d_in[3];
    const float* gamma = (const float*)d_in[4];
    const float* beta = (const float*)d_in[5];
    const float* convw = (const float*)d_in[6];
    const float* convb = (const float*)d_in[7];
    const float* hid_w = (const float*)d_in[8];
    const float* hid_b = (const float*)d_in[9];
    const float* out_w = (const float*)d_in[10];
    const float* out_b = (const float*)d_in[11];
    float* out = (float*)d_out;

    char* ws = (char*)d_ws;
    size_t off = 0;
    int*   rowptr  = (int*)(ws + off);   off = alignup(off + ((size_t)NN + 1) * 4, 256);
    float* dinv    = (float*)(ws + off); off = alignup(off + (size_t)NN * 4, 256);
    float* dsq     = (float*)(ws + off); off = alignup(off + (size_t)NN * 4, 256);
    float* S1      = (float*)(ws + off); off = alignup(off + (size_t)NN * 4, 256);
    int*   wcur    = (int*)(ws + off);   off = alignup(off + NWIN * 4, 256);
    int*   wbase   = (int*)(ws + off);   off = alignup(off + NWIN * 4, 256);
    int*   csr     = (int*)(ws + off);   off = alignup(off + (size_t)NE * 4, 256);
    double* pooled = (double*)(ws + off); off = alignup(off + (size_t)NG * CH * 8, 256);
    float* partial = (float*)(ws + off); off = alignup(off + (size_t)NBLKP * 2 * CH * 4, 256);
    double* stats  = (double*)(ws + off); off = alignup(off + 2 * CH * 8, 256);
    // union region: bucket (build-time) overlaps hA/hB (layer-time; written after build)
    unsigned int* bucket = (unsigned int*)(ws + off);   // 512*18432*4 = 37.75MB
    float* hA      = (float*)(ws + off);
    float* hB      = (float*)(ws + off + alignup((size_t)NN * CH * 4, 256));

    const int B = 256;

    k_init<<<(NG * CH + B - 1) / B, B, 0, stream>>>(wcur, pooled);
    k_part<<<NPBLK, 1024, 0, stream>>>(srcp, dstp, wcur, bucket);
    k_wscan<<<1, NWIN, 0, stream>>>(wcur, wbase, rowptr);
    k_sortwin<<<NWIN, 1024, 0, stream>>>(wcur, wbase, bucket, rowptr, dinv, dsq, csr);
    k_s1<<<NBLK, B, 0, stream>>>(rowptr, csr, dinv, S1);
    // ---- bucket dead from here; hA/hB live ----
    k_embed<<<NBLK, B, 0, stream>>>(x, emb, dinv, hA, partial);
    k_rstats<<<16, 256, 0, stream>>>(partial, NBLK, stats);

    float* hc = hA;
    float* hn = hB;
    for (int i = 0; i < NCONV; i++) {
        if (i < NCONV - 1) {
            k_gconv<<<NBLKP, B, 0, stream>>>(rowptr, csr, dinv, dsq, S1, stats,
                                             gamma + i * CH, beta + i * CH,
                                             convw + i * CH * CH, convb + i * CH,
                                             hc, hn, partial);
            k_rstats<<<16, 256, 0, stream>>>(partial, NBLKP, stats);
            float* tmp = hc; hc = hn; hn = tmp;
        } else {
            k_gpool<<<NBLKP, B, 0, stream>>>(rowptr, csr, dinv, dsq, S1, stats,
                                             gamma + i * CH, beta + i * CH,
                                             convw + i * CH * CH, convb + i * CH,
                                             hc, batch, pooled);
        }
    }
    k_mlp<<<NG, HID, 0, stream>>>(pooled, hid_w, hid_b, out_w, out_b, out);
}